// Round 5
// baseline (67.798 us; speedup 1.0000x reference)
//
#include <hip/hip_runtime.h>

// ZBL repulsion energy: out[b] = sum_{n,k} KEHALF * f(a*d) * Zi*Zj*mask / d
// B=16, N=8192, K=128 in the bench (shapes derived from in_sizes).
//
// Round-5 design (round-4 post-mortem: async-LDS pipeline was too shallow and
// killed occupancy -> latency-bound at 20% occupancy / 14% HBM):
//  - back to VGPR streaming with explicit register double-buffer: prefetch
//    group g+1 (int4+float4+float4) while computing group g; no barriers in
//    the main loop; 256-thread blocks.
//  - VALU cut: f(ad) = KEHALF * sum_i w_i exp(-s_i ad) is 1-D in
//    ad = (zpi+zpj)*m*d  ->  1024-entry {f, df} LUT in LDS, linear interp.
//    Replaces 4 exp2 + 12 mul/fma per edge with 1 ds_read_b64 + ~6 VALU.
//  - LDS: 16KB atom tab (u16) + 8KB LUT = 24.6KB -> 6 blocks/CU = 75% occ.

#define KEHALF_F 7.199822675975274f
#define LOG2E_F  1.4426950408889634f
#define LUTN     1024
#define LUT_ADMAX 80.0f
#define EPP      1024     // edges per pass per block (256 thr x 4)
#define PASSES   8        // passes per block (span = 8192 edges)

__device__ __forceinline__ float softplus_f(float x) {
    return (x > 20.f) ? x : log1pf(__expf(x));
}

// ---------------- precompute: scalars + packed u16 per-atom table ----------------
__global__ void zbl_pre(const int* __restrict__ zn,
                        const float* __restrict__ adiv,
                        const float* __restrict__ apow,
                        const float* __restrict__ c1, const float* __restrict__ c2,
                        const float* __restrict__ c3, const float* __restrict__ c4,
                        const float* __restrict__ a1, const float* __restrict__ a2,
                        const float* __restrict__ a3, const float* __restrict__ a4,
                        unsigned short* __restrict__ packed, float* __restrict__ scal,
                        int total_atoms)
{
    int i = blockIdx.x * blockDim.x + threadIdx.x;
    const float spa = softplus_f(apow[0]);
    const float sad = softplus_f(adiv[0]);
    const float qb  = sad;                                  // Z=1 -> zps=sad
    const float qmax = sad * __expf(spa * __logf(94.f));
    const float qs  = (qmax - qb) * (1.f / 511.f);
    if (i == 0) {
        float s1 = softplus_f(c1[0]), s2 = softplus_f(c2[0]);
        float s3 = softplus_f(c3[0]), s4 = softplus_f(c4[0]);
        float inv = KEHALF_F / (s1 + s2 + s3 + s4);         // fold KEHALF
        scal[0] = sad;
        scal[1] = s1 * inv;
        scal[2] = s2 * inv;
        scal[3] = s3 * inv;
        scal[4] = s4 * inv;
        scal[5] = -softplus_f(a1[0]) * LOG2E_F;             // exp2 form (fallback)
        scal[6] = -softplus_f(a2[0]) * LOG2E_F;
        scal[7] = -softplus_f(a3[0]) * LOG2E_F;
        scal[8] = -softplus_f(a4[0]) * LOG2E_F;
        scal[9]  = qb;
        scal[10] = qs;
    }
    if (i < total_atoms) {
        unsigned int Z = (unsigned int)zn[i];
        float Zf = (float)Z;
        float zps = sad * __expf(spa * __logf(Zf));         // sp(adiv) * Z^sp(apow)
        float qf = (zps - qb) / qs;
        int q = (int)(qf + 0.5f);
        if (q < 0) q = 0;
        if (q > 511) q = 511;
        packed[i] = (unsigned short)(((unsigned)q << 7) | (Z & 0x7Fu));
    }
}

// ---------------- LUT builder: f(x) = KEHALF * sum w_i exp(-s_i x) ----------------
__global__ void zbl_lut_k(const float* __restrict__ c1, const float* __restrict__ c2,
                          const float* __restrict__ c3, const float* __restrict__ c4,
                          const float* __restrict__ a1, const float* __restrict__ a2,
                          const float* __restrict__ a3, const float* __restrict__ a4,
                          float2* __restrict__ lut)
{
    int i = blockIdx.x * blockDim.x + threadIdx.x;
    if (i >= LUTN) return;
    float s1 = softplus_f(c1[0]), s2 = softplus_f(c2[0]);
    float s3 = softplus_f(c3[0]), s4 = softplus_f(c4[0]);
    float inv = KEHALF_F / (s1 + s2 + s3 + s4);
    float w1 = s1 * inv, w2 = s2 * inv, w3 = s3 * inv, w4 = s4 * inv;
    float g1 = -softplus_f(a1[0]), g2 = -softplus_f(a2[0]);
    float g3 = -softplus_f(a3[0]), g4 = -softplus_f(a4[0]);
    const float h = LUT_ADMAX / (float)(LUTN - 1);
    float x0 = (float)i * h, x1 = x0 + h;
    float f0 = w1 * __expf(g1 * x0) + w2 * __expf(g2 * x0)
             + w3 * __expf(g3 * x0) + w4 * __expf(g4 * x0);
    float f1 = w1 * __expf(g1 * x1) + w2 * __expf(g2 * x1)
             + w3 * __expf(g3 * x1) + w4 * __expf(g4 * x1);
    lut[i] = make_float2(f0, f1 - f0);
}

// ---------------- main: reg double-buffered streaming + LDS tab/LUT ----------------
extern __shared__ char smem[];   // [N u16 tab][LUTN float2 lut]

__global__ __launch_bounds__(256, 6) void zbl_main_l(
        const int*            __restrict__ neighbors,
        const float*          __restrict__ mask,
        const float*          __restrict__ dist,
        const unsigned short* __restrict__ packed,
        const float2*         __restrict__ lutg,
        const float*          __restrict__ scal,
        float*                __restrict__ out,
        int N, int kshift, int epb, int passes)
{
    unsigned short* tab = (unsigned short*)smem;
    float2*         lut = (float2*)(smem + (size_t)N * 2);

    const int tid = threadIdx.x;
    const int b   = blockIdx.y;
    const int span = passes << 10;                       // EPP = 1024
    const int r0   = blockIdx.x * span + tid * 4;        // within-batch edge idx
    const size_t base = (size_t)b * epb + r0;
    const int*   nb = neighbors + base;
    const float* mk = mask      + base;
    const float* ds = dist      + base;

    // issue group-0 streaming loads first (complete during staging)
    int4   ci = *(const int4*)nb;
    float4 cm = *(const float4*)mk;
    float4 cd = *(const float4*)ds;

    // stage atom table + LUT into LDS (coalesced 16B copies)
    {
        const uint4* s4 = (const uint4*)(packed + (size_t)b * N);
        uint4* t4 = (uint4*)tab;
        for (int i = tid, e = N >> 3; i < e; i += 256) t4[i] = s4[i];
        const uint4* l4 = (const uint4*)lutg;
        uint4* d4 = (uint4*)lut;
        for (int i = tid, e = LUTN >> 1; i < e; i += 256) d4[i] = l4[i];
    }
    const float qb = scal[9], qs = scal[10];
    __syncthreads();

    const float lscale = (float)(LUTN - 1) * (1.0f / LUT_ADMAX);
    const float tmax   = (float)(LUTN - 1) - 1.0f;

    float acc = 0.f;

    auto compute = [&](int g, int4 gi, float4 gm, float4 gd) {
        const unsigned int wi = tab[(r0 + (g << 10)) >> kshift];
        const float zpi = fmaf((float)(wi >> 7), qs, qb);
        const float Zi  = (float)(wi & 0x7Fu);
        const int   idxs[4] = { gi.x, gi.y, gi.z, gi.w };
        const float mm[4]   = { gm.x, gm.y, gm.z, gm.w };
        const float dd[4]   = { gd.x, gd.y, gd.z, gd.w };
        #pragma unroll
        for (int u = 0; u < 4; ++u) {
            const unsigned int wj = tab[idxs[u]];
            const float zpj = fmaf((float)(wj >> 7), qs, qb);
            const float Zj  = (float)(wj & 0x7Fu);
            const float m = mm[u], d = dd[u];
            const float zz = Zi * Zj * m;
            const float ad = (zpi + zpj) * (m * d);
            float t = fminf(ad * lscale, tmax);
            const int   it = (int)t;
            const float fr = t - (float)it;
            const float2 lv = lut[it];
            const float f  = fmaf(fr, lv.y, lv.x);
            const float gc = f * zz * __builtin_amdgcn_rcpf(d);
            acc += (m != 0.f) ? gc : 0.f;
        }
    };

    for (int g = 0; g < passes - 1; ++g) {
        const int go = (g + 1) << 10;
        int4   ni = *(const int4*)(nb + go);      // prefetch next group
        float4 nm = *(const float4*)(mk + go);
        float4 nd = *(const float4*)(ds + go);
        compute(g, ci, cm, cd);
        ci = ni; cm = nm; cd = nd;
    }
    compute(passes - 1, ci, cm, cd);

    // wave reduce, cross-wave via LDS, one atomic per block
    #pragma unroll
    for (int off = 32; off > 0; off >>= 1) acc += __shfl_down(acc, off);
    __shared__ float wsum[4];
    const int w = tid >> 6, lane = tid & 63;
    if (lane == 0) wsum[w] = acc;
    __syncthreads();
    if (tid == 0) atomicAdd(&out[b], wsum[0] + wsum[1] + wsum[2] + wsum[3]);
}

// ---------------- fallback (generic shapes, not used in bench) ----------------
__global__ void zbl_fallback(const int* __restrict__ neighbors,
                             const float* __restrict__ mask,
                             const float* __restrict__ dist,
                             const unsigned short* __restrict__ packed,
                             const float* __restrict__ scal,
                             float* __restrict__ out,
                             int N, int K, int epb, int total_edges)
{
    const int e = blockIdx.x * blockDim.x + threadIdx.x;
    if (e >= total_edges) return;
    const float w1 = scal[1], w2 = scal[2], w3 = scal[3], w4 = scal[4];
    const float e1 = scal[5], e2 = scal[6], e3 = scal[7], e4 = scal[8];
    const float qb = scal[9], qs = scal[10];
    const int b = e / epb;
    const int n = (e - b * epb) / K;
    const unsigned int wi = packed[(size_t)b * N + n];
    const unsigned int wj = packed[(size_t)b * N + neighbors[e]];
    const float zpi = fmaf((float)(wi >> 7), qs, qb);
    const float zpj = fmaf((float)(wj >> 7), qs, qb);
    const float Zi = (float)(wi & 0x7Fu), Zj = (float)(wj & 0x7Fu);
    const float m = mask[e], d = dist[e];
    const float a  = (zpi + zpj) * m;
    const float ad = a * d;
    const float f = w1 * exp2f(e1 * ad) + w2 * exp2f(e2 * ad)
                  + w3 * exp2f(e3 * ad) + w4 * exp2f(e4 * ad);
    const float corr = (m != 0.f) ? (f * Zi * Zj * m / d) : 0.f;
    if (corr != 0.f) atomicAdd(&out[b], corr);
}

extern "C" void kernel_launch(void* const* d_in, const int* in_sizes, int n_in,
                              void* d_out, int out_size, void* d_ws, size_t ws_size,
                              hipStream_t stream) {
    const int*   neighbors = (const int*)  d_in[0];
    const float* nb_mask   = (const float*)d_in[1];
    const int*   zn        = (const int*)  d_in[2];
    const float* dist      = (const float*)d_in[3];
    const float* adiv = (const float*)d_in[4];
    const float* apow = (const float*)d_in[5];
    const float* c1 = (const float*)d_in[6];
    const float* c2 = (const float*)d_in[7];
    const float* c3 = (const float*)d_in[8];
    const float* c4 = (const float*)d_in[9];
    const float* a1 = (const float*)d_in[10];
    const float* a2 = (const float*)d_in[11];
    const float* a3 = (const float*)d_in[12];
    const float* a4 = (const float*)d_in[13];

    const int total_edges = in_sizes[0];   // B*N*K
    const int total_atoms = in_sizes[2];   // B*N
    const int B = out_size;                // [B,1] fp32 output
    const int N = total_atoms / B;
    const int K = total_edges / total_atoms;
    const int epb = N * K;

    float*          scal   = (float*)d_ws;                         // 11 f32
    unsigned short* packed = (unsigned short*)((char*)d_ws + 64);  // B*N u16
    const size_t lut_off   = 64 + (size_t)total_atoms * 2;
    float2*         lutg   = (float2*)((char*)d_ws + ((lut_off + 15) & ~(size_t)15));

    hipMemsetAsync(d_out, 0, (size_t)out_size * sizeof(float), stream);

    {
        const int threads = 256;
        const int blocks = (total_atoms + threads - 1) / threads;
        zbl_pre<<<blocks, threads, 0, stream>>>(zn, adiv, apow, c1, c2, c3, c4,
                                                a1, a2, a3, a4,
                                                packed, scal, total_atoms);
    }
    zbl_lut_k<<<LUTN / 256, 256, 0, stream>>>(c1, c2, c3, c4, a1, a2, a3, a4, lutg);

    int kshift = 0;
    while ((1 << kshift) < K && kshift < 30) kshift++;
    const bool kpow2 = ((1 << kshift) == K);

    const size_t lds_bytes = (size_t)N * 2 + (size_t)LUTN * 8;
    const bool fast = kpow2 && (K % 4 == 0) && (N % 8 == 0) &&
                      (epb % (EPP * PASSES) == 0) &&
                      (lds_bytes <= 64 * 1024) &&
                      (((lut_off + 15) & ~(size_t)15) + LUTN * 8 <= ws_size);
    if (fast) {
        const int bpb = epb / (EPP * PASSES);          // blocks per batch
        dim3 grid(bpb, B);
        zbl_main_l<<<grid, 256, lds_bytes, stream>>>(
            neighbors, nb_mask, dist, packed, lutg, scal, (float*)d_out,
            N, kshift, epb, PASSES);
    } else {
        const int threads = 256;
        const int blocks = (total_edges + threads - 1) / threads;
        zbl_fallback<<<blocks, threads, 0, stream>>>(
            neighbors, nb_mask, dist, packed, scal, (float*)d_out,
            N, K, epb, total_edges);
    }
}